// Round 2
// baseline (7341.447 us; speedup 1.0000x reference)
//
#include <hip/hip_runtime.h>
#include <math.h>

#define BSZ 512
#define SEQ 128
#define FF  136
#define HH  128

// ---------------- transpose (384x128 -> 128x384) ----------------
__global__ __launch_bounds__(256) void k_transpose384(const float* __restrict__ A,
                                                      float* __restrict__ At) {
    int i = blockIdx.x * 256 + threadIdx.x;          // over 384*128
    if (i < 384 * 128) {
        int r = i >> 7, c = i & 127;
        At[c * 384 + r] = A[i];
    }
}

// ---------------- fused doc FNN + V + GI precompute ----------------
__global__ __launch_bounds__(256) void k_docvgi(
    const float* __restrict__ br,
    const float* __restrict__ fW1, const float* __restrict__ fb1,
    const float* __restrict__ fW2, const float* __restrict__ fb2,
    const float* __restrict__ comW1,
    const float* __restrict__ WihT, const float* __restrict__ bih,
    float* __restrict__ V, float* __restrict__ GI)
{
    __shared__ float xs[32][FF];
    __shared__ float hs[32][HH];
    __shared__ float ds[32][HH];
    int row0 = blockIdx.x * 32;
    int t = threadIdx.x;
    const float* src = br + (size_t)row0 * FF;
    for (int i = t; i < 32 * FF; i += 256) xs[i / FF][i % FF] = src[i];
    __syncthreads();
    int j = t & 127, rg = t >> 7;
    float acc[16];
#pragma unroll
    for (int r = 0; r < 16; r++) acc[r] = 0.f;
    for (int k = 0; k < FF; k++) {
        float w = fW1[k * HH + j];
#pragma unroll
        for (int r = 0; r < 16; r++) acc[r] += xs[rg + 2 * r][k] * w;
    }
    {
        float bb = fb1[j];
#pragma unroll
        for (int r = 0; r < 16; r++) hs[rg + 2 * r][j] = fmaxf(acc[r] + bb, 0.f);
    }
    __syncthreads();
#pragma unroll
    for (int r = 0; r < 16; r++) acc[r] = 0.f;
    for (int k = 0; k < HH; k++) {
        float w = fW2[k * HH + j];
#pragma unroll
        for (int r = 0; r < 16; r++) acc[r] += hs[rg + 2 * r][k] * w;
    }
    {
        float bb = fb2[j];
#pragma unroll
        for (int r = 0; r < 16; r++)
            ds[rg + 2 * r][j] = 1.f / (1.f + expf(-(acc[r] + bb)));
    }
    __syncthreads();
#pragma unroll
    for (int r = 0; r < 16; r++) acc[r] = 0.f;
    for (int k = 0; k < HH; k++) {
        float w = comW1[k * HH + j];
#pragma unroll
        for (int r = 0; r < 16; r++) acc[r] += ds[rg + 2 * r][k] * w;
    }
#pragma unroll
    for (int r = 0; r < 16; r++) V[(size_t)(row0 + rg + 2 * r) * HH + j] = acc[r];
    for (int p = 0; p < 3; p++) {
        int jj = p * HH + j;
#pragma unroll
        for (int r = 0; r < 16; r++) acc[r] = 0.f;
        for (int k = 0; k < HH; k++) {
            float w = WihT[k * 384 + jj];
#pragma unroll
            for (int r = 0; r < 16; r++) acc[r] += ds[rg + 2 * r][k] * w;
        }
        float bb = bih[jj];
#pragma unroll
        for (int r = 0; r < 16; r++)
            GI[(size_t)(row0 + rg + 2 * r) * 384 + jj] = acc[r] + bb;
    }
}

// ---------------- grouped scan: 2 batch elems per block, 1024 threads ----------------
__global__ __launch_bounds__(1024, 4) void k_scan2(
    const float* __restrict__ br,
    const float* __restrict__ cntW1, const float* __restrict__ cntb1,
    const float* __restrict__ cntW2, const float* __restrict__ cntb2,
    const float* __restrict__ comW1, const float* __restrict__ comb1,
    const float* __restrict__ comW2,
    const float* __restrict__ WhhT, const float* __restrict__ gbhh,
    const float* __restrict__ V, const float* __restrict__ GI,
    float* __restrict__ out)
{
    __shared__ double svS[2][HH];         // running sum path: sum_masked(br) @ W1b
    __shared__ double mxvS[2][HH];        // mx @ W1a, maintained incrementally
    __shared__ float  Vl[2][SEQ][HH + 1]; // padded: stride 129 -> conflict-free
    __shared__ float  pp[2][8][HH];       // matvec partials (slots 4..5 reused in F)
    __shared__ float  ghp[2][2][384];     // GRU gh partials
    __shared__ float  hS[2][HH], crS[2][HH], uS[2][HH];
    __shared__ float  scS[2][SEQ];        // doubles as a1 (lifetimes disjoint)
    __shared__ float  mxS[2][FF];
    __shared__ int    mxiS[2][FF];
    __shared__ int    maskS[2][SEQ];
    __shared__ int    chgF[2][FF];
    __shared__ float  chgD[2][FF];        // also used as colsum staging at init
    __shared__ int    chgN[2];
    __shared__ float  pw[SEQ], c2S[HH];
    __shared__ int    selS[2];

    const int b0 = blockIdx.x * 2;
    const int t  = threadIdx.x;
    const float* brB0 = br + (size_t)b0 * SEQ * FF;
    const float* brB1 = br + (size_t)(b0 + 1) * SEQ * FF;

    // ---- init: V tiles, col max/sum, misc ----
    for (int g = 0; g < 2; g++) {
        const float* Vb = V + (size_t)(b0 + g) * SEQ * HH;
        for (int idx = t; idx < SEQ * HH; idx += 1024)
            Vl[g][idx >> 7][idx & 127] = Vb[idx];
    }
    {
        int g = t >> 9, r = t & 511;
        if (r < FF) {
            const float* bp = (g ? brB1 : brB0) + r;
            float cs = 0.f; float mx = -__builtin_huge_valf(); int mi = 0;
            for (int s = 0; s < SEQ; s++) {
                float v = bp[s * FF];
                cs += v;
                if (v > mx) { mx = v; mi = s; }
            }
            mxS[g][r] = mx; mxiS[g][r] = mi; chgD[g][r] = cs;
        }
    }
    if (t < SEQ) pw[t] = powf(0.9f, (float)t);
    if (t < HH)  c2S[t] = comW2[t];
    if (t < 256) { int g = t >> 7, j = t & 127; hS[g][j] = 0.f; maskS[g][j] = 1; }
    __syncthreads();
    if (t < 256) {
        int g = t >> 7, j = t & 127;
        double am = 0.0, as = 0.0;
        for (int f = 0; f < FF; f++) {
            am += (double)mxS[g][f]  * (double)cntW1[f * HH + j];
            as += (double)chgD[g][f] * (double)cntW1[(FF + f) * HH + j];
        }
        mxvS[g][j] = am; svS[g][j] = as;
    }
    __syncthreads();

    for (int i = 0; i < SEQ; i++) {
        // ---- A: a1 = relu(mxv + sv/cnt + b1)   (elementwise!) ----
        if (t < 256) {
            int g = t >> 7, j = t & 127;
            if (j == 0) chgN[g] = 0;
            float pre = (float)(mxvS[g][j] + svS[g][j] / (double)(SEQ - i)) + cntb1[j];
            scS[g][j] = fmaxf(pre, 0.f);     // a1 alias
        }
        __syncthreads();

        // ---- B: cr-pre = a1 @ cntW2 (both g share each weight load) ----
        {
            int kg = t >> 7, j = t & 127, k0 = kg * 16;
            float a0 = 0.f, a1 = 0.f;
            for (int m = 0; m < 16; m++) {
                int k = k0 + m;
                float w = cntW2[k * HH + j];
                a0 += scS[0][k] * w; a1 += scS[1][k] * w;
            }
            pp[0][kg][j] = a0; pp[1][kg][j] = a1;
        }
        __syncthreads();
        if (t < 256) {
            int g = t >> 7, j = t & 127;
            float s = pp[g][0][j] + pp[g][1][j] + pp[g][2][j] + pp[g][3][j]
                    + pp[g][4][j] + pp[g][5][j] + pp[g][6][j] + pp[g][7][j] + cntb2[j];
            crS[g][j] = 1.f / (1.f + expf(-s));
        }
        __syncthreads();

        // ---- C: u = cr @ comW1[128:256] + h @ comW1[256:384] ----
        {
            int kg = t >> 7, j = t & 127, k0 = kg * 32;
            const float* base = comW1 + (size_t)(HH + k0) * HH + j;
            const float* s0p, * s1p;
            if (kg < 4) { s0p = crS[0] + k0; s1p = crS[1] + k0; }
            else        { s0p = hS[0] + (k0 - 128); s1p = hS[1] + (k0 - 128); }
            float a0 = 0.f, a1 = 0.f;
            for (int m = 0; m < 32; m++) {
                float w = base[m * HH];
                a0 += s0p[m] * w; a1 += s1p[m] * w;
            }
            pp[0][kg][j] = a0; pp[1][kg][j] = a1;
        }
        __syncthreads();
        if (t < 256) {
            int g = t >> 7, j = t & 127;
            uS[g][j] = pp[g][0][j] + pp[g][1][j] + pp[g][2][j] + pp[g][3][j]
                     + pp[g][4][j] + pp[g][5][j] + pp[g][6][j] + pp[g][7][j] + comb1[j];
        }
        __syncthreads();

        // ---- D: scores[s] = sum_k c2[k]*relu(V[s][k]+u[k]) ----
        {
            int g = t >> 9, r = t & 511, kg = r >> 7, s = r & 127, k0 = kg * 32;
            float acc = 0.f;
            for (int m = 0; m < 32; m++) {
                int k = k0 + m;
                acc += c2S[k] * fmaxf(Vl[g][s][k] + uS[g][k], 0.f);
            }
            pp[g][kg][s] = acc;
        }
        __syncthreads();
        if (t < 256) {
            int g = t >> 7, s = t & 127;
            scS[g][s] = pp[g][0][s] + pp[g][1][s] + pp[g][2][s] + pp[g][3][s];
        }
        __syncthreads();

        // ---- E: masked argmax per g (one wave each) ----
        {
            int gg = -1, lane = 0;
            if (t < 64)                { gg = 0; lane = t; }
            else if (t >= 512 && t < 576) { gg = 1; lane = t - 512; }
            if (gg >= 0) {
                float v1 = maskS[gg][lane]      ? scS[gg][lane]      : -__builtin_huge_valf();
                float v2 = maskS[gg][lane + 64] ? scS[gg][lane + 64] : -__builtin_huge_valf();
                float v; int idx;
                if (v2 > v1) { v = v2; idx = lane + 64; } else { v = v1; idx = lane; }
                for (int off = 32; off >= 1; off >>= 1) {
                    float ov = __shfl_down(v, off);
                    int   oi = __shfl_down(idx, off);
                    if (ov > v || (ov == v && oi < idx)) { v = ov; idx = oi; }
                }
                if (lane == 0) {
                    selS[gg] = idx;
                    maskS[gg][idx] = 0;
                    out[(size_t)(b0 + gg) * SEQ + idx] = pw[i];
                }
            }
        }
        __syncthreads();

        // ---- F: per-feature max maintenance + selected-row @ W1b partials ----
        if (i < SEQ - 1) {
            int g = t >> 9, r = t & 511;
            int sel = selS[g];
            const float* brB = g ? brB1 : brB0;
            if (r < FF) {
                int f = r;
                if (sel == mxiS[g][f]) {
                    float om = mxS[g][f];
                    float mx = -__builtin_huge_valf(); int mi = 0;
                    for (int s = 0; s < SEQ; s++) {
                        if (maskS[g][s]) {
                            float v = brB[s * FF + f];
                            if (v > mx) { mx = v; mi = s; }
                        }
                    }
                    mxS[g][f] = mx; mxiS[g][f] = mi;
                    int e = atomicAdd(&chgN[g], 1);
                    chgF[g][e] = f; chgD[g][e] = mx - om;
                }
            } else if (r >= 256) {
                int kg = (r >> 7) - 2, j = r & 127;   // kg in {0,1}
                const float* brow = brB + (size_t)sel * FF;
                float acc = 0.f;
                int k0 = kg * 68;
                for (int m = 0; m < 68; m++) {
                    int k = k0 + m;
                    acc += brow[k] * cntW1[(FF + k) * HH + j];
                }
                pp[g][4 + kg][j] = acc;
            }
        }
        __syncthreads();

        // ---- F2: apply incremental updates to sv, mxv ----
        if (i < SEQ - 1 && t < 256) {
            int g = t >> 7, j = t & 127;
            svS[g][j] -= (double)(pp[g][4][j] + pp[g][5][j]);
            int n = chgN[g];
            double acc = mxvS[g][j];
            for (int e = 0; e < n; e++)
                acc += (double)chgD[g][e] * (double)cntW1[chgF[g][e] * HH + j];
            mxvS[g][j] = acc;
        }
        __syncthreads();

        // ---- G: GRU gh = h @ Whh^T (both g share weight loads) ----
        if (i < SEQ - 1) {
            if (t < 768) {
                int kg = t / 384, jj = t % 384, k0 = kg * 64;
                const float* Wp = WhhT + (size_t)k0 * 384 + jj;
                float a0 = 0.f, a1 = 0.f;
                for (int m = 0; m < 64; m++) {
                    float w = Wp[m * 384];
                    a0 += hS[0][k0 + m] * w; a1 += hS[1][k0 + m] * w;
                }
                ghp[0][kg][jj] = a0; ghp[1][kg][jj] = a1;
            }
        }
        __syncthreads();
        if (i < SEQ - 1 && t < 256) {
            int g = t >> 7, j = t & 127;
            int sel = selS[g];
            const float* gir = GI + ((size_t)(b0 + g) * SEQ + sel) * 384;
            float ghr = ghp[g][0][j]       + ghp[g][1][j]       + gbhh[j];
            float ghz = ghp[g][0][HH + j]  + ghp[g][1][HH + j]  + gbhh[HH + j];
            float ghn = ghp[g][0][2*HH + j]+ ghp[g][1][2*HH + j]+ gbhh[2*HH + j];
            float rr = 1.f / (1.f + expf(-(gir[j] + ghr)));
            float zz = 1.f / (1.f + expf(-(gir[HH + j] + ghz)));
            float nn = tanhf(gir[2 * HH + j] + rr * ghn);
            hS[g][j] = (1.f - zz) * nn + zz * hS[g][j];
        }
        __syncthreads();
    }
}

extern "C" void kernel_launch(void* const* d_in, const int* in_sizes, int n_in,
                              void* d_out, int out_size, void* d_ws, size_t ws_size,
                              hipStream_t stream) {
    (void)in_sizes; (void)n_in; (void)out_size; (void)ws_size;
    const float* br    = (const float*)d_in[0];
    const float* fnnW1 = (const float*)d_in[2];
    const float* fnnb1 = (const float*)d_in[3];
    const float* fnnW2 = (const float*)d_in[4];
    const float* fnnb2 = (const float*)d_in[5];
    const float* cntW1 = (const float*)d_in[6];
    const float* cntb1 = (const float*)d_in[7];
    const float* cntW2 = (const float*)d_in[8];
    const float* cntb2 = (const float*)d_in[9];
    const float* comW1 = (const float*)d_in[10];
    const float* comb1 = (const float*)d_in[11];
    const float* comW2 = (const float*)d_in[12];
    const float* Wih   = (const float*)d_in[14];
    const float* Whh   = (const float*)d_in[15];
    const float* bih   = (const float*)d_in[16];
    const float* bhh   = (const float*)d_in[17];

    float* ws   = (float*)d_ws;
    float* V    = ws;                         // 512*128*128      =  8,388,608 f
    float* GI   = ws + 8388608;               // 512*128*384      = 25,165,824 f
    float* WihT = ws + 8388608 + 25165824;    // 128*384          =     49,152 f
    float* WhhT = WihT + 49152;               // 128*384          =     49,152 f

    hipLaunchKernelGGL(k_transpose384, dim3(192), dim3(256), 0, stream, Wih, WihT);
    hipLaunchKernelGGL(k_transpose384, dim3(192), dim3(256), 0, stream, Whh, WhhT);
    hipLaunchKernelGGL(k_docvgi, dim3(2048), dim3(256), 0, stream,
                       br, fnnW1, fnnb1, fnnW2, fnnb2, comW1, WihT, bih, V, GI);
    hipLaunchKernelGGL(k_scan2, dim3(BSZ / 2), dim3(1024), 0, stream,
                       br, cntW1, cntb1, cntW2, cntb2, comW1, comb1, comW2,
                       WhhT, bhh, V, GI, (float*)d_out);
}